// Round 1
// baseline (244.161 us; speedup 1.0000x reference)
//
#include <hip/hip_runtime.h>
#include <hip/hip_bf16.h>

#define Bsz 4
#define Ssz 2048
#define Dsz 256
#define Hh 8
#define HDd 32

typedef __attribute__((ext_vector_type(8))) short bh8;
typedef __attribute__((ext_vector_type(4))) float f4;
typedef __attribute__((ext_vector_type(4))) short sh4;

#define SCAL 0.17677669529663687f   /* 32^-0.5 */
#define LOG2E 1.4426950408889634f
#define QSCALE (SCAL * LOG2E)

__device__ __forceinline__ short f2bf(float f) {
    union { float f; unsigned u; } x; x.f = f;
    unsigned r = x.u + 0x7fffu + ((x.u >> 16) & 1u);
    return (short)(r >> 16);
}

// ---------------- weight prep: transpose to [n][d] bf16, fold q scaling ----------------
__global__ __launch_bounds__(256) void prep_w(
    const float* __restrict__ Wq, const float* __restrict__ Wk,
    const float* __restrict__ Wv, const float* __restrict__ Wo,
    const float* __restrict__ bq, short* __restrict__ Wt,
    float* __restrict__ bqs, int* __restrict__ flag)
{
    int t = blockIdx.x * 256 + threadIdx.x;   // t = d*256 + n
    int d = t >> 8, n = t & 255;
    int o = n * 256 + d;
    Wt[o]          = f2bf(Wq[t] * QSCALE);
    Wt[65536 + o]  = f2bf(Wk[t]);
    Wt[131072 + o] = f2bf(Wv[t]);
    Wt[196608 + o] = f2bf(Wo[t]);
    if (t == 0) *flag = 0;
    if (t < 256) bqs[t] = bq[t] * QSCALE;
}

// ---------------- mask scan: set flag if any nonzero ----------------
__global__ __launch_bounds__(256) void scan_mask(const float* __restrict__ mask,
                                                 int* __restrict__ flag)
{
    const size_t N4 = (size_t)Bsz * Ssz * Ssz / 4;
    const f4* m4 = (const f4*)mask;
    bool nz = false;
    for (size_t i = blockIdx.x * 256 + threadIdx.x; i < N4; i += (size_t)gridDim.x * 256) {
        f4 v = m4[i];
        nz |= (v[0] != 0.f) || (v[1] != 0.f) || (v[2] != 0.f) || (v[3] != 0.f);
    }
    if (nz) atomicOr(flag, 1);
}

// ---------------- fused QKV projection ----------------
// grid (M/64, 3): y=0 -> Q (scaled, [B,H,S,32]), y=1 -> K ([B,H,S,32]), y=2 -> V^T ([B,H,32,S])
__global__ __launch_bounds__(256) void qkv_gemm(
    const float* __restrict__ hid, const float* __restrict__ pos,
    const short* __restrict__ Wt, const float* __restrict__ bqs,
    const float* __restrict__ bk, const float* __restrict__ bv,
    short* __restrict__ Q, short* __restrict__ K, short* __restrict__ Vt)
{
    const int ky = blockIdx.y;
    const int w = threadIdx.x >> 6, lane = threadIdx.x & 63;
    const int lg = lane >> 4, lr = lane & 15;
    const int m0 = blockIdx.x * 64 + w * 16;
    const short* W = Wt + ky * 65536;
    f4 acc[16];
#pragma unroll
    for (int t = 0; t < 16; t++) acc[t] = (f4){0.f, 0.f, 0.f, 0.f};

    const float* ap0 = hid + (size_t)(m0 + lr) * 256 + lg * 8;
    const float* pp0 = pos + (size_t)(m0 + lr) * 256 + lg * 8;
#pragma unroll
    for (int k0 = 0; k0 < 256; k0 += 32) {
        f4 a1 = *(const f4*)(ap0 + k0);
        f4 a2 = *(const f4*)(ap0 + k0 + 4);
        if (ky < 2) {
            f4 p1 = *(const f4*)(pp0 + k0);
            f4 p2 = *(const f4*)(pp0 + k0 + 4);
            a1 += p1; a2 += p2;
        }
        bh8 af;
#pragma unroll
        for (int j = 0; j < 4; j++) { af[j] = f2bf(a1[j]); af[4 + j] = f2bf(a2[j]); }
#pragma unroll
        for (int nt = 0; nt < 16; nt++) {
            bh8 bf = *(const bh8*)(W + (nt * 16 + lr) * 256 + k0 + lg * 8);
            acc[nt] = __builtin_amdgcn_mfma_f32_16x16x32_bf16(af, bf, acc[nt], 0, 0, 0);
        }
    }
    const int b = m0 >> 11;
    const int s0 = m0 & 2047;
#pragma unroll
    for (int nt = 0; nt < 16; nt++) {
        const int n = nt * 16 + lr;
        const int h = n >> 5, hd = n & 31;
#pragma unroll
        for (int r = 0; r < 4; r++) {
            const int s = s0 + lg * 4 + r;
            float v = acc[nt][r];
            if (ky == 0) {
                v += bqs[n];
                Q[(((size_t)(b * Hh + h)) * Ssz + s) * HDd + hd] = f2bf(v);
            } else if (ky == 1) {
                v += bk[n];
                K[(((size_t)(b * Hh + h)) * Ssz + s) * HDd + hd] = f2bf(v);
            } else {
                v += bv[n];
                Vt[(((size_t)(b * Hh + h)) * HDd + hd) * Ssz + s] = f2bf(v);
            }
        }
    }
}

// ---------------- flash attention ----------------
// grid (S/64, B*H), 4 waves/block, each wave owns 16 q rows.
__global__ __launch_bounds__(256) void attn(
    const short* __restrict__ Q, const short* __restrict__ Kb,
    const short* __restrict__ Vt, const float* __restrict__ mask,
    const int* __restrict__ flag, short* __restrict__ ctx)
{
    const int bh = blockIdx.y, b = bh >> 3, h = bh & 7;
    const int w = threadIdx.x >> 6, lane = threadIdx.x & 63;
    const int lg = lane >> 4, lr = lane & 15;
    const int q0 = blockIdx.x * 64 + w * 16;
    const short* Qp = Q + ((size_t)bh * Ssz + q0) * HDd;
    const short* Kp = Kb + (size_t)bh * Ssz * HDd;
    const short* Vp = Vt + (size_t)bh * HDd * Ssz;
    const float* mrow = mask + ((size_t)b * Ssz + q0 + lr) * Ssz;
    const bool um = (*flag) != 0;

    bh8 qf = *(const bh8*)(Qp + lr * HDd + lg * 8);
    f4 acc0 = {0.f, 0.f, 0.f, 0.f}, acc1 = {0.f, 0.f, 0.f, 0.f};
    float mx = -1e30f, sum = 0.f;
    const f4 z = {0.f, 0.f, 0.f, 0.f};

    for (int kb = 0; kb < Ssz; kb += 32) {
        bh8 k0 = *(const bh8*)(Kp + (size_t)(kb + lr) * HDd + lg * 8);
        bh8 k1 = *(const bh8*)(Kp + (size_t)(kb + 16 + lr) * HDd + lg * 8);
        // scores (log2 domain): D[key][q], q = lr, keys = kb + lg*4 + r (+16 for sc1)
        f4 sc0 = __builtin_amdgcn_mfma_f32_16x16x32_bf16(k0, qf, z, 0, 0, 0);
        f4 sc1 = __builtin_amdgcn_mfma_f32_16x16x32_bf16(k1, qf, z, 0, 0, 0);
        if (um) {
            f4 mv0 = *(const f4*)(mrow + kb + lg * 4);
            f4 mv1 = *(const f4*)(mrow + kb + 16 + lg * 4);
            sc0 += mv0 * LOG2E; sc1 += mv1 * LOG2E;
        }
        float tm = fmaxf(fmaxf(fmaxf(sc0[0], sc0[1]), fmaxf(sc0[2], sc0[3])),
                         fmaxf(fmaxf(sc1[0], sc1[1]), fmaxf(sc1[2], sc1[3])));
        tm = fmaxf(tm, __shfl_xor(tm, 16));
        tm = fmaxf(tm, __shfl_xor(tm, 32));
        float nm = fmaxf(mx, tm);
        float alpha = exp2f(mx - nm);
        mx = nm;
        float p[8];
#pragma unroll
        for (int j = 0; j < 4; j++) { p[j] = exp2f(sc0[j] - nm); p[4 + j] = exp2f(sc1[j] - nm); }
        float ps = (p[0] + p[1]) + (p[2] + p[3]) + ((p[4] + p[5]) + (p[6] + p[7]));
        ps += __shfl_xor(ps, 16);
        ps += __shfl_xor(ps, 32);
        sum = sum * alpha + ps;
#pragma unroll
        for (int r = 0; r < 4; r++) { acc0[r] *= alpha; acc1[r] *= alpha; }
        bh8 pf;
#pragma unroll
        for (int j = 0; j < 8; j++) pf[j] = f2bf(p[j]);
        // V^T fragments: A slot (row=hd=lr, k=key'(lg,j)=kb+lg*4+(j&3)+16*(j>>2)) — same packing as pf
        const short* vp0 = Vp + (size_t)lr * Ssz + kb + lg * 4;
        const short* vp1 = Vp + (size_t)(16 + lr) * Ssz + kb + lg * 4;
        sh4 va = *(const sh4*)(vp0), vb = *(const sh4*)(vp0 + 16);
        sh4 vc = *(const sh4*)(vp1), vd = *(const sh4*)(vp1 + 16);
        bh8 v0, v1;
#pragma unroll
        for (int j = 0; j < 4; j++) { v0[j] = va[j]; v0[4 + j] = vb[j]; v1[j] = vc[j]; v1[4 + j] = vd[j]; }
        acc0 = __builtin_amdgcn_mfma_f32_16x16x32_bf16(v0, pf, acc0, 0, 0, 0);
        acc1 = __builtin_amdgcn_mfma_f32_16x16x32_bf16(v1, pf, acc1, 0, 0, 0);
    }
    float inv = 1.f / sum;
    // ctx^T regs: lane holds ctx[q=lr][hd = lg*4 + r (+16)]
    short* cp = ctx + ((size_t)(b * Ssz + q0 + lr)) * Dsz + h * HDd + lg * 4;
#pragma unroll
    for (int r = 0; r < 4; r++) {
        cp[r]      = f2bf(acc0[r] * inv);
        cp[16 + r] = f2bf(acc1[r] * inv);
    }
}

// ---------------- output projection ----------------
__global__ __launch_bounds__(256) void out_gemm(
    const short* __restrict__ ctx, const short* __restrict__ WtO,
    const float* __restrict__ bo, float* __restrict__ out)
{
    const int w = threadIdx.x >> 6, lane = threadIdx.x & 63;
    const int lg = lane >> 4, lr = lane & 15;
    const int m0 = blockIdx.x * 64 + w * 16;
    f4 acc[16];
#pragma unroll
    for (int t = 0; t < 16; t++) acc[t] = (f4){0.f, 0.f, 0.f, 0.f};
    const short* ap = ctx + (size_t)(m0 + lr) * 256 + lg * 8;
#pragma unroll
    for (int k0 = 0; k0 < 256; k0 += 32) {
        bh8 af = *(const bh8*)(ap + k0);
#pragma unroll
        for (int nt = 0; nt < 16; nt++) {
            bh8 bf = *(const bh8*)(WtO + (nt * 16 + lr) * 256 + k0 + lg * 8);
            acc[nt] = __builtin_amdgcn_mfma_f32_16x16x32_bf16(af, bf, acc[nt], 0, 0, 0);
        }
    }
#pragma unroll
    for (int nt = 0; nt < 16; nt++) {
        const int n = nt * 16 + lr;
        const float bias = bo[n];
#pragma unroll
        for (int r = 0; r < 4; r++) {
            out[(size_t)(m0 + lg * 4 + r) * 256 + n] = acc[nt][r] + bias;
        }
    }
}

extern "C" void kernel_launch(void* const* d_in, const int* in_sizes, int n_in,
                              void* d_out, int out_size, void* d_ws, size_t ws_size,
                              hipStream_t stream)
{
    const float* hid  = (const float*)d_in[0];
    const float* pos  = (const float*)d_in[1];
    const float* mask = (const float*)d_in[2];
    const float* Wq   = (const float*)d_in[3];
    const float* bq   = (const float*)d_in[4];
    const float* Wk   = (const float*)d_in[5];
    const float* bk   = (const float*)d_in[6];
    const float* Wv   = (const float*)d_in[7];
    const float* bv   = (const float*)d_in[8];
    const float* Wo   = (const float*)d_in[9];
    const float* bo   = (const float*)d_in[10];
    float* out = (float*)d_out;

    char* ws = (char*)d_ws;
    short* Wt   = (short*)(ws);                    // 512 KB: Wq^T,Wk^T,Wv^T,Wo^T bf16
    float* bqs  = (float*)(ws + (512 << 10));      // 1 KB
    int*   flag = (int*)  (ws + (516 << 10));      // 4 B
    short* Qb   = (short*)(ws + (1  << 20));       // 4 MB  [B,H,S,32] bf16
    short* Kb   = (short*)(ws + (5  << 20));       // 4 MB  [B,H,S,32] bf16
    short* Vtb  = (short*)(ws + (9  << 20));       // 4 MB  [B,H,32,S] bf16
    short* ctxb = (short*)(ws + (13 << 20));       // 4 MB  [B,S,256] bf16

    prep_w<<<256, 256, 0, stream>>>(Wq, Wk, Wv, Wo, bq, Wt, bqs, flag);
    scan_mask<<<2048, 256, 0, stream>>>(mask, flag);
    qkv_gemm<<<dim3(128, 3), 256, 0, stream>>>(hid, pos, Wt, bqs, bk, bv, Qb, Kb, Vtb);
    attn<<<dim3(32, 32), 256, 0, stream>>>(Qb, Kb, Vtb, mask, flag, ctxb);
    out_gemm<<<128, 256, 0, stream>>>(ctxb, Wt + 196608, bo, out);
}

// Round 2
// 187.171 us; speedup vs baseline: 1.3045x; 1.3045x over previous
//
#include <hip/hip_runtime.h>
#include <hip/hip_bf16.h>

#define Bsz 4
#define Ssz 2048
#define Dsz 256
#define Hh 8
#define HDd 32

typedef __attribute__((ext_vector_type(8))) short bh8;
typedef __attribute__((ext_vector_type(4))) float f4;

#define SCAL 0.17677669529663687f   /* 32^-0.5 */
#define LOG2E 1.4426950408889634f
#define QSCALE (SCAL * LOG2E)

__device__ __forceinline__ short f2bf(float f) {
    union { float f; unsigned u; } x; x.f = f;
    unsigned r = x.u + 0x7fffu + ((x.u >> 16) & 1u);
    return (short)(r >> 16);
}

__device__ __forceinline__ float fexp2(float x) {
#if __has_builtin(__builtin_amdgcn_exp2f)
    return __builtin_amdgcn_exp2f(x);
#else
    float r; asm("v_exp_f32 %0, %1" : "=v"(r) : "v"(x)); return r;
#endif
}

__device__ __forceinline__ unsigned cvtpk(float lo, float hi) {
    unsigned r; asm("v_cvt_pk_bf16_f32 %0, %1, %2" : "=v"(r) : "v"(lo), "v"(hi));
    return r;
}

// ---------------- weight prep: transpose to [n][d] bf16, fold q scaling ----------------
__global__ __launch_bounds__(256) void prep_w(
    const float* __restrict__ Wq, const float* __restrict__ Wk,
    const float* __restrict__ Wv, const float* __restrict__ Wo,
    const float* __restrict__ bq, short* __restrict__ Wt,
    float* __restrict__ bqs, int* __restrict__ flag)
{
    int t = blockIdx.x * 256 + threadIdx.x;   // t = d*256 + n
    int d = t >> 8, n = t & 255;
    int o = n * 256 + d;
    Wt[o]          = f2bf(Wq[t] * QSCALE);
    Wt[65536 + o]  = f2bf(Wk[t]);
    Wt[131072 + o] = f2bf(Wv[t]);
    Wt[196608 + o] = f2bf(Wo[t]);
    if (t == 0) *flag = 0;
    if (t < 256) bqs[t] = bq[t] * QSCALE;
}

// ---------------- mask scan: set flag if any nonzero ----------------
__global__ __launch_bounds__(256) void scan_mask(const float* __restrict__ mask,
                                                 int* __restrict__ flag)
{
    const size_t N4 = (size_t)Bsz * Ssz * Ssz / 4;
    const f4* m4 = (const f4*)mask;
    bool nz = false;
    for (size_t i = blockIdx.x * 256 + threadIdx.x; i < N4; i += (size_t)gridDim.x * 256) {
        f4 v = m4[i];
        nz |= (v[0] != 0.f) || (v[1] != 0.f) || (v[2] != 0.f) || (v[3] != 0.f);
    }
    if (nz) atomicOr(flag, 1);
}

// ---------------- fused QKV projection ----------------
// grid (M/64, 3): y=0 -> Q (scaled, [B,H,S,32]), y=1 -> K ([B,H,S,32]),
// y=2 -> V^T ([B,H,32,S]) with keys pre-permuted per 32-block into MFMA k-slot order.
__global__ __launch_bounds__(256) void qkv_gemm(
    const float* __restrict__ hid, const float* __restrict__ pos,
    const short* __restrict__ Wt, const float* __restrict__ bqs,
    const float* __restrict__ bk, const float* __restrict__ bv,
    short* __restrict__ Q, short* __restrict__ K, short* __restrict__ Vt)
{
    const int ky = blockIdx.y;
    const int w = threadIdx.x >> 6, lane = threadIdx.x & 63;
    const int lg = lane >> 4, lr = lane & 15;
    const int m0 = blockIdx.x * 64 + w * 16;
    const short* W = Wt + ky * 65536;
    f4 acc[16];
#pragma unroll
    for (int t = 0; t < 16; t++) acc[t] = (f4){0.f, 0.f, 0.f, 0.f};

    const float* ap0 = hid + (size_t)(m0 + lr) * 256 + lg * 8;
    const float* pp0 = pos + (size_t)(m0 + lr) * 256 + lg * 8;
#pragma unroll
    for (int k0 = 0; k0 < 256; k0 += 32) {
        f4 a1 = *(const f4*)(ap0 + k0);
        f4 a2 = *(const f4*)(ap0 + k0 + 4);
        if (ky < 2) {
            f4 p1 = *(const f4*)(pp0 + k0);
            f4 p2 = *(const f4*)(pp0 + k0 + 4);
            a1 += p1; a2 += p2;
        }
        union { unsigned u[4]; bh8 v; } af;
        af.u[0] = cvtpk(a1[0], a1[1]); af.u[1] = cvtpk(a1[2], a1[3]);
        af.u[2] = cvtpk(a2[0], a2[1]); af.u[3] = cvtpk(a2[2], a2[3]);
#pragma unroll
        for (int nt = 0; nt < 16; nt++) {
            bh8 bf = *(const bh8*)(W + (nt * 16 + lr) * 256 + k0 + lg * 8);
            acc[nt] = __builtin_amdgcn_mfma_f32_16x16x32_bf16(af.v, bf, acc[nt], 0, 0, 0);
        }
    }
    const int b = m0 >> 11;
    const int s0 = m0 & 2047;
#pragma unroll
    for (int nt = 0; nt < 16; nt++) {
        const int n = nt * 16 + lr;
        const int h = n >> 5, hd = n & 31;
#pragma unroll
        for (int r = 0; r < 4; r++) {
            const int s = s0 + lg * 4 + r;
            float v = acc[nt][r];
            if (ky == 0) {
                v += bqs[n];
                Q[(((size_t)(b * Hh + h)) * Ssz + s) * HDd + hd] = f2bf(v);
            } else if (ky == 1) {
                v += bk[n];
                K[(((size_t)(b * Hh + h)) * Ssz + s) * HDd + hd] = f2bf(v);
            } else {
                v += bv[n];
                // permute key within its 32-block into MFMA k-slot order:
                // pos = slot so that attn's bh8 load at [kb + lg*8] is the A-fragment
                int s32 = s & 31;
                int ps = ((s32 & 15) >> 2) * 8 + (s32 >> 4) * 4 + (s32 & 3);
                Vt[(((size_t)(b * Hh + h)) * HDd + hd) * Ssz + (s & ~31) + ps] = f2bf(v);
            }
        }
    }
}

// ---------------- flash attention ----------------
// grid (S/64, B*H), 4 waves/block, each wave owns 16 q rows, KV tile = 64.
__global__ __launch_bounds__(256) void attn(
    const short* __restrict__ Q, const short* __restrict__ Kb,
    const short* __restrict__ Vt, const float* __restrict__ mask,
    const int* __restrict__ flag, short* __restrict__ ctx)
{
    const int bh = blockIdx.y, b = bh >> 3, h = bh & 7;
    const int w = threadIdx.x >> 6, lane = threadIdx.x & 63;
    const int lg = lane >> 4, lr = lane & 15;
    const int q0 = blockIdx.x * 64 + w * 16;
    const short* Qp = Q + ((size_t)bh * Ssz + q0) * HDd;
    const short* Kp = Kb + (size_t)bh * Ssz * HDd;
    const short* Vp = Vt + (size_t)bh * HDd * Ssz;
    const float* mrow = mask + ((size_t)b * Ssz + q0 + lr) * Ssz;
    const bool um = (*flag) != 0;

    bh8 qf = *(const bh8*)(Qp + lr * HDd + lg * 8);
    f4 acc0 = {0.f, 0.f, 0.f, 0.f}, acc1 = {0.f, 0.f, 0.f, 0.f};
    float mx = -1e30f, sumP = 0.f;
    const f4 z = {0.f, 0.f, 0.f, 0.f};

    for (int kb = 0; kb < Ssz; kb += 64) {
        // ---- loads first (independent of all compute) ----
        const short* kp = Kp + (size_t)kb * HDd + lg * 8;
        bh8 k0 = *(const bh8*)(kp + (size_t)lr * HDd);
        bh8 k1 = *(const bh8*)(kp + (size_t)(16 + lr) * HDd);
        bh8 k2 = *(const bh8*)(kp + (size_t)(32 + lr) * HDd);
        bh8 k3 = *(const bh8*)(kp + (size_t)(48 + lr) * HDd);
        const short* vp = Vp + (size_t)lr * Ssz + kb + lg * 8;
        bh8 v00 = *(const bh8*)(vp);
        bh8 v01 = *(const bh8*)(vp + 32);
        bh8 v10 = *(const bh8*)(vp + (size_t)16 * Ssz);
        bh8 v11 = *(const bh8*)(vp + (size_t)16 * Ssz + 32);

        // ---- scores (exp2 domain): D[key][q], q = lr ----
        f4 s0 = __builtin_amdgcn_mfma_f32_16x16x32_bf16(k0, qf, z, 0, 0, 0);
        f4 s1 = __builtin_amdgcn_mfma_f32_16x16x32_bf16(k1, qf, z, 0, 0, 0);
        f4 s2 = __builtin_amdgcn_mfma_f32_16x16x32_bf16(k2, qf, z, 0, 0, 0);
        f4 s3 = __builtin_amdgcn_mfma_f32_16x16x32_bf16(k3, qf, z, 0, 0, 0);
        if (um) {
            f4 m0v = *(const f4*)(mrow + kb + lg * 4);
            f4 m1v = *(const f4*)(mrow + kb + 16 + lg * 4);
            f4 m2v = *(const f4*)(mrow + kb + 32 + lg * 4);
            f4 m3v = *(const f4*)(mrow + kb + 48 + lg * 4);
            s0 += m0v * LOG2E; s1 += m1v * LOG2E; s2 += m2v * LOG2E; s3 += m3v * LOG2E;
        }

        // ---- per-lane max of 16; cross-lane + rescale only if needed (T13) ----
        float ta = fmaxf(fmaxf(s0[0], s0[1]), fmaxf(s0[2], s0[3]));
        float tb = fmaxf(fmaxf(s1[0], s1[1]), fmaxf(s1[2], s1[3]));
        float tc = fmaxf(fmaxf(s2[0], s2[1]), fmaxf(s2[2], s2[3]));
        float td = fmaxf(fmaxf(s3[0], s3[1]), fmaxf(s3[2], s3[3]));
        float tm = fmaxf(fmaxf(ta, tb), fmaxf(tc, td));
        if (!__all(tm <= mx + 8.f)) {
            tm = fmaxf(tm, __shfl_xor(tm, 16));
            tm = fmaxf(tm, __shfl_xor(tm, 32));
            float nm = fmaxf(mx, tm);
            float alpha = fexp2(mx - nm);
            mx = nm;
#pragma unroll
            for (int r = 0; r < 4; r++) { acc0[r] *= alpha; acc1[r] *= alpha; }
            sumP *= alpha;
        }

        // ---- P = exp2(S - mx) ----
        float p[16];
#pragma unroll
        for (int j = 0; j < 4; j++) {
            p[j]      = fexp2(s0[j] - mx);
            p[4 + j]  = fexp2(s1[j] - mx);
            p[8 + j]  = fexp2(s2[j] - mx);
            p[12 + j] = fexp2(s3[j] - mx);
        }
        sumP += ((p[0] + p[1]) + (p[2] + p[3])) + ((p[4] + p[5]) + (p[6] + p[7]))
              + ((p[8] + p[9]) + (p[10] + p[11])) + ((p[12] + p[13]) + (p[14] + p[15]));

        union { unsigned u[4]; bh8 v; } pf0, pf1;
        pf0.u[0] = cvtpk(p[0], p[1]);   pf0.u[1] = cvtpk(p[2], p[3]);
        pf0.u[2] = cvtpk(p[4], p[5]);   pf0.u[3] = cvtpk(p[6], p[7]);
        pf1.u[0] = cvtpk(p[8], p[9]);   pf1.u[1] = cvtpk(p[10], p[11]);
        pf1.u[2] = cvtpk(p[12], p[13]); pf1.u[3] = cvtpk(p[14], p[15]);

        // ---- PV: V^T pre-permuted, fragments load directly ----
        acc0 = __builtin_amdgcn_mfma_f32_16x16x32_bf16(v00, pf0.v, acc0, 0, 0, 0);
        acc0 = __builtin_amdgcn_mfma_f32_16x16x32_bf16(v01, pf1.v, acc0, 0, 0, 0);
        acc1 = __builtin_amdgcn_mfma_f32_16x16x32_bf16(v10, pf0.v, acc1, 0, 0, 0);
        acc1 = __builtin_amdgcn_mfma_f32_16x16x32_bf16(v11, pf1.v, acc1, 0, 0, 0);
    }

    // deferred cross-lane sum reduction (alpha was lg-uniform throughout)
    float sum = sumP;
    sum += __shfl_xor(sum, 16);
    sum += __shfl_xor(sum, 32);
    float inv = 1.f / sum;

    // ctx regs: lane holds ctx[q=lr][hd = lg*4 + r (+16)]
    short* cp = ctx + ((size_t)(b * Ssz + q0 + lr)) * Dsz + h * HDd + lg * 4;
#pragma unroll
    for (int r = 0; r < 4; r++) {
        cp[r]      = f2bf(acc0[r] * inv);
        cp[16 + r] = f2bf(acc1[r] * inv);
    }
}

// ---------------- output projection ----------------
__global__ __launch_bounds__(256) void out_gemm(
    const short* __restrict__ ctx, const short* __restrict__ WtO,
    const float* __restrict__ bo, float* __restrict__ out)
{
    const int w = threadIdx.x >> 6, lane = threadIdx.x & 63;
    const int lg = lane >> 4, lr = lane & 15;
    const int m0 = blockIdx.x * 64 + w * 16;
    f4 acc[16];
#pragma unroll
    for (int t = 0; t < 16; t++) acc[t] = (f4){0.f, 0.f, 0.f, 0.f};
    const short* ap = ctx + (size_t)(m0 + lr) * 256 + lg * 8;
#pragma unroll
    for (int k0 = 0; k0 < 256; k0 += 32) {
        bh8 af = *(const bh8*)(ap + k0);
#pragma unroll
        for (int nt = 0; nt < 16; nt++) {
            bh8 bf = *(const bh8*)(WtO + (nt * 16 + lr) * 256 + k0 + lg * 8);
            acc[nt] = __builtin_amdgcn_mfma_f32_16x16x32_bf16(af, bf, acc[nt], 0, 0, 0);
        }
    }
#pragma unroll
    for (int nt = 0; nt < 16; nt++) {
        const int n = nt * 16 + lr;
        const float bias = bo[n];
#pragma unroll
        for (int r = 0; r < 4; r++) {
            out[(size_t)(m0 + lg * 4 + r) * 256 + n] = acc[nt][r] + bias;
        }
    }
}

extern "C" void kernel_launch(void* const* d_in, const int* in_sizes, int n_in,
                              void* d_out, int out_size, void* d_ws, size_t ws_size,
                              hipStream_t stream)
{
    const float* hid  = (const float*)d_in[0];
    const float* pos  = (const float*)d_in[1];
    const float* mask = (const float*)d_in[2];
    const float* Wq   = (const float*)d_in[3];
    const float* bq   = (const float*)d_in[4];
    const float* Wk   = (const float*)d_in[5];
    const float* bk   = (const float*)d_in[6];
    const float* Wv   = (const float*)d_in[7];
    const float* bv   = (const float*)d_in[8];
    const float* Wo   = (const float*)d_in[9];
    const float* bo   = (const float*)d_in[10];
    float* out = (float*)d_out;

    char* ws = (char*)d_ws;
    short* Wt   = (short*)(ws);                    // 512 KB: Wq^T,Wk^T,Wv^T,Wo^T bf16
    float* bqs  = (float*)(ws + (512 << 10));      // 1 KB
    int*   flag = (int*)  (ws + (516 << 10));      // 4 B
    short* Qb   = (short*)(ws + (1  << 20));       // 4 MB  [B,H,S,32] bf16
    short* Kb   = (short*)(ws + (5  << 20));       // 4 MB  [B,H,S,32] bf16
    short* Vtb  = (short*)(ws + (9  << 20));       // 4 MB  [B,H,32,S] bf16 (k-slot permuted)
    short* ctxb = (short*)(ws + (13 << 20));       // 4 MB  [B,S,256] bf16

    prep_w<<<256, 256, 0, stream>>>(Wq, Wk, Wv, Wo, bq, Wt, bqs, flag);
    scan_mask<<<2048, 256, 0, stream>>>(mask, flag);
    qkv_gemm<<<dim3(128, 3), 256, 0, stream>>>(hid, pos, Wt, bqs, bk, bv, Qb, Kb, Vtb);
    attn<<<dim3(32, 32), 256, 0, stream>>>(Qb, Kb, Vtb, mask, flag, ctxb);
    out_gemm<<<128, 256, 0, stream>>>(ctxb, Wt + 196608, bo, out);
}

// Round 3
// 183.029 us; speedup vs baseline: 1.3340x; 1.0226x over previous
//
#include <hip/hip_runtime.h>
#include <hip/hip_bf16.h>

#define Bsz 4
#define Ssz 2048
#define Dsz 256
#define Hh 8
#define HDd 32

typedef __attribute__((ext_vector_type(8))) short bh8;
typedef __attribute__((ext_vector_type(4))) float f4;
typedef __attribute__((ext_vector_type(2))) unsigned u2;

#define SCAL 0.17677669529663687f   /* 32^-0.5 */
#define LOG2E 1.4426950408889634f
#define QSCALE (SCAL * LOG2E)

__device__ __forceinline__ short f2bf(float f) {
    union { float f; unsigned u; } x; x.f = f;
    unsigned r = x.u + 0x7fffu + ((x.u >> 16) & 1u);
    return (short)(r >> 16);
}

__device__ __forceinline__ float bf2f(short s) {
    union { unsigned u; float f; } x;
    x.u = ((unsigned)(unsigned short)s) << 16;
    return x.f;
}

__device__ __forceinline__ float fexp2(float x) {
#if __has_builtin(__builtin_amdgcn_exp2f)
    return __builtin_amdgcn_exp2f(x);
#else
    float r; asm("v_exp_f32 %0, %1" : "=v"(r) : "v"(x)); return r;
#endif
}

__device__ __forceinline__ unsigned cvtpk(float lo, float hi) {
    unsigned r; asm("v_cvt_pk_bf16_f32 %0, %1, %2" : "=v"(r) : "v"(lo), "v"(hi));
    return r;
}

// ---------------- weight prep: transpose to [n][d] bf16, fold q scaling ----------------
__global__ __launch_bounds__(256) void prep_w(
    const float* __restrict__ Wq, const float* __restrict__ Wk,
    const float* __restrict__ Wv, const float* __restrict__ Wo,
    const float* __restrict__ bq, short* __restrict__ Wt,
    float* __restrict__ bqs, int* __restrict__ flag)
{
    int t = blockIdx.x * 256 + threadIdx.x;   // t = d*256 + n
    int d = t >> 8, n = t & 255;
    int o = n * 256 + d;
    Wt[o]          = f2bf(Wq[t] * QSCALE);
    Wt[65536 + o]  = f2bf(Wk[t]);
    Wt[131072 + o] = f2bf(Wv[t]);
    Wt[196608 + o] = f2bf(Wo[t]);
    if (t == 0) *flag = 0;
    if (t < 256) bqs[t] = bq[t] * QSCALE;
}

// ---------------- mask scan: set flag if any nonzero ----------------
__global__ __launch_bounds__(256) void scan_mask(const float* __restrict__ mask,
                                                 int* __restrict__ flag)
{
    const size_t N4 = (size_t)Bsz * Ssz * Ssz / 4;
    const f4* m4 = (const f4*)mask;
    bool nz = false;
    for (size_t i = blockIdx.x * 256 + threadIdx.x; i < N4; i += (size_t)gridDim.x * 256) {
        f4 v = m4[i];
        nz |= (v[0] != 0.f) || (v[1] != 0.f) || (v[2] != 0.f) || (v[3] != 0.f);
    }
    if (nz) atomicOr(flag, 1);
}

// ---------------- fused QKV projection (1-wave blocks for CU balance) ----------------
// grid (S*B/16, 3): y=0 -> Q (scaled, [B,H,S,32]), y=1 -> K ([B,H,S,32]),
// y=2 -> V^T ([B,H,32,S]) with keys pre-permuted per 32-block into MFMA k-slot order.
__global__ __launch_bounds__(64) void qkv_gemm(
    const float* __restrict__ hid, const float* __restrict__ pos,
    const short* __restrict__ Wt, const float* __restrict__ bqs,
    const float* __restrict__ bk, const float* __restrict__ bv,
    short* __restrict__ Q, short* __restrict__ K, short* __restrict__ Vt)
{
    const int ky = blockIdx.y;
    const int lane = threadIdx.x;
    const int lg = lane >> 4, lr = lane & 15;
    const int m0 = blockIdx.x * 16;
    const short* W = Wt + ky * 65536;
    f4 acc[16];
#pragma unroll
    for (int t = 0; t < 16; t++) acc[t] = (f4){0.f, 0.f, 0.f, 0.f};

    const float* ap0 = hid + (size_t)(m0 + lr) * 256 + lg * 8;
    const float* pp0 = pos + (size_t)(m0 + lr) * 256 + lg * 8;
#pragma unroll
    for (int k0 = 0; k0 < 256; k0 += 32) {
        f4 a1 = *(const f4*)(ap0 + k0);
        f4 a2 = *(const f4*)(ap0 + k0 + 4);
        if (ky < 2) {
            f4 p1 = *(const f4*)(pp0 + k0);
            f4 p2 = *(const f4*)(pp0 + k0 + 4);
            a1 += p1; a2 += p2;
        }
        union { unsigned u[4]; bh8 v; } af;
        af.u[0] = cvtpk(a1[0], a1[1]); af.u[1] = cvtpk(a1[2], a1[3]);
        af.u[2] = cvtpk(a2[0], a2[1]); af.u[3] = cvtpk(a2[2], a2[3]);
#pragma unroll
        for (int nt = 0; nt < 16; nt++) {
            bh8 bf = *(const bh8*)(W + (nt * 16 + lr) * 256 + k0 + lg * 8);
            acc[nt] = __builtin_amdgcn_mfma_f32_16x16x32_bf16(af.v, bf, acc[nt], 0, 0, 0);
        }
    }
    const int b = m0 >> 11;
    const int s0 = m0 & 2047;
#pragma unroll
    for (int nt = 0; nt < 16; nt++) {
        const int n = nt * 16 + lr;
        const int h = n >> 5, hd = n & 31;
#pragma unroll
        for (int r = 0; r < 4; r++) {
            const int s = s0 + lg * 4 + r;
            float v = acc[nt][r];
            if (ky == 0) {
                v += bqs[n];
                Q[(((size_t)(b * Hh + h)) * Ssz + s) * HDd + hd] = f2bf(v);
            } else if (ky == 1) {
                v += bk[n];
                K[(((size_t)(b * Hh + h)) * Ssz + s) * HDd + hd] = f2bf(v);
            } else {
                v += bv[n];
                // permute key within its 32-block into MFMA k-slot order:
                // pos = slot so that attn's bh8 load at [kb + lg*8] is the A-fragment
                int s32 = s & 31;
                int ps = ((s32 & 15) >> 2) * 8 + (s32 >> 4) * 4 + (s32 & 3);
                Vt[(((size_t)(b * Hh + h)) * HDd + hd) * Ssz + (s & ~31) + ps] = f2bf(v);
            }
        }
    }
}

// ---------------- flash attention ----------------
// grid (S/64, B*H, NS), 4 waves/block, each wave owns 16 q rows, KV tile = 64.
// NS=1: writes normalized ctx directly. NS=2: writes bf16 partial acc + (mx,sum).
template<int NS>
__global__ __launch_bounds__(256) void attn(
    const short* __restrict__ Q, const short* __restrict__ Kb,
    const short* __restrict__ Vt, const float* __restrict__ mask,
    const int* __restrict__ flag, short* __restrict__ ctx,
    short* __restrict__ pacc, float* __restrict__ pms)
{
    const int bh = blockIdx.y, b = bh >> 3, h = bh & 7;
    const int w = threadIdx.x >> 6, lane = threadIdx.x & 63;
    const int lg = lane >> 4, lr = lane & 15;
    const int q0 = blockIdx.x * 64 + w * 16;
    const int kz0 = blockIdx.z * (Ssz / NS);
    const int kz1 = kz0 + (Ssz / NS);
    const short* Qp = Q + ((size_t)bh * Ssz + q0) * HDd;
    const short* Kp = Kb + (size_t)bh * Ssz * HDd;
    const short* Vp = Vt + (size_t)bh * HDd * Ssz;
    const float* mrow = mask + ((size_t)b * Ssz + q0 + lr) * Ssz;
    const bool um = (*flag) != 0;

    bh8 qf = *(const bh8*)(Qp + lr * HDd + lg * 8);
    f4 acc0 = {0.f, 0.f, 0.f, 0.f}, acc1 = {0.f, 0.f, 0.f, 0.f};
    float mx = -1e30f, sumP = 0.f;
    const f4 z = {0.f, 0.f, 0.f, 0.f};

    // K prefetch pipeline: loads for tile kb land while tile kb-64 computes
    const short* kpb = Kp + lg * 8;
    bh8 nk0 = *(const bh8*)(kpb + (size_t)(kz0 + lr) * HDd);
    bh8 nk1 = *(const bh8*)(kpb + (size_t)(kz0 + 16 + lr) * HDd);
    bh8 nk2 = *(const bh8*)(kpb + (size_t)(kz0 + 32 + lr) * HDd);
    bh8 nk3 = *(const bh8*)(kpb + (size_t)(kz0 + 48 + lr) * HDd);

    for (int kb = kz0; kb < kz1; kb += 64) {
        bh8 k0 = nk0, k1 = nk1, k2 = nk2, k3 = nk3;
        // prefetch next K tile (last iter over-reads into adjacent ws region: harmless)
        const short* kp = kpb + (size_t)(kb + 64) * HDd;
        nk0 = *(const bh8*)(kp + (size_t)lr * HDd);
        nk1 = *(const bh8*)(kp + (size_t)(16 + lr) * HDd);
        nk2 = *(const bh8*)(kp + (size_t)(32 + lr) * HDd);
        nk3 = *(const bh8*)(kp + (size_t)(48 + lr) * HDd);
        // V loads for current tile (consumed after softmax -> latency mostly hidden)
        const short* vp = Vp + (size_t)lr * Ssz + kb + lg * 8;
        bh8 v00 = *(const bh8*)(vp);
        bh8 v01 = *(const bh8*)(vp + 32);
        bh8 v10 = *(const bh8*)(vp + (size_t)16 * Ssz);
        bh8 v11 = *(const bh8*)(vp + (size_t)16 * Ssz + 32);

        // ---- scores (exp2 domain): D[key][q], q = lr ----
        f4 s0 = __builtin_amdgcn_mfma_f32_16x16x32_bf16(k0, qf, z, 0, 0, 0);
        f4 s1 = __builtin_amdgcn_mfma_f32_16x16x32_bf16(k1, qf, z, 0, 0, 0);
        f4 s2 = __builtin_amdgcn_mfma_f32_16x16x32_bf16(k2, qf, z, 0, 0, 0);
        f4 s3 = __builtin_amdgcn_mfma_f32_16x16x32_bf16(k3, qf, z, 0, 0, 0);
        if (um) {
            f4 m0v = *(const f4*)(mrow + kb + lg * 4);
            f4 m1v = *(const f4*)(mrow + kb + 16 + lg * 4);
            f4 m2v = *(const f4*)(mrow + kb + 32 + lg * 4);
            f4 m3v = *(const f4*)(mrow + kb + 48 + lg * 4);
            s0 += m0v * LOG2E; s1 += m1v * LOG2E; s2 += m2v * LOG2E; s3 += m3v * LOG2E;
        }

        // ---- per-lane max of 16; cross-lane + rescale only if needed (T13) ----
        float ta = fmaxf(fmaxf(s0[0], s0[1]), fmaxf(s0[2], s0[3]));
        float tb = fmaxf(fmaxf(s1[0], s1[1]), fmaxf(s1[2], s1[3]));
        float tc = fmaxf(fmaxf(s2[0], s2[1]), fmaxf(s2[2], s2[3]));
        float td = fmaxf(fmaxf(s3[0], s3[1]), fmaxf(s3[2], s3[3]));
        float tm = fmaxf(fmaxf(ta, tb), fmaxf(tc, td));
        if (!__all(tm <= mx + 8.f)) {
            tm = fmaxf(tm, __shfl_xor(tm, 16));
            tm = fmaxf(tm, __shfl_xor(tm, 32));
            float nm = fmaxf(mx, tm);
            float alpha = fexp2(mx - nm);
            mx = nm;
#pragma unroll
            for (int r = 0; r < 4; r++) { acc0[r] *= alpha; acc1[r] *= alpha; }
            sumP *= alpha;
        }

        // ---- P = exp2(S - mx) ----
        float p[16];
#pragma unroll
        for (int j = 0; j < 4; j++) {
            p[j]      = fexp2(s0[j] - mx);
            p[4 + j]  = fexp2(s1[j] - mx);
            p[8 + j]  = fexp2(s2[j] - mx);
            p[12 + j] = fexp2(s3[j] - mx);
        }
        sumP += ((p[0] + p[1]) + (p[2] + p[3])) + ((p[4] + p[5]) + (p[6] + p[7]))
              + ((p[8] + p[9]) + (p[10] + p[11])) + ((p[12] + p[13]) + (p[14] + p[15]));

        union { unsigned u[4]; bh8 v; } pf0, pf1;
        pf0.u[0] = cvtpk(p[0], p[1]);   pf0.u[1] = cvtpk(p[2], p[3]);
        pf0.u[2] = cvtpk(p[4], p[5]);   pf0.u[3] = cvtpk(p[6], p[7]);
        pf1.u[0] = cvtpk(p[8], p[9]);   pf1.u[1] = cvtpk(p[10], p[11]);
        pf1.u[2] = cvtpk(p[12], p[13]); pf1.u[3] = cvtpk(p[14], p[15]);

        // ---- PV: V^T pre-permuted, fragments load directly ----
        acc0 = __builtin_amdgcn_mfma_f32_16x16x32_bf16(v00, pf0.v, acc0, 0, 0, 0);
        acc0 = __builtin_amdgcn_mfma_f32_16x16x32_bf16(v01, pf1.v, acc0, 0, 0, 0);
        acc1 = __builtin_amdgcn_mfma_f32_16x16x32_bf16(v10, pf0.v, acc1, 0, 0, 0);
        acc1 = __builtin_amdgcn_mfma_f32_16x16x32_bf16(v11, pf1.v, acc1, 0, 0, 0);
    }

    // deferred cross-lane sum reduction (alpha was row-uniform throughout)
    float sum = sumP;
    sum += __shfl_xor(sum, 16);
    sum += __shfl_xor(sum, 32);

    if constexpr (NS == 1) {
        float inv = 1.f / sum;
        // ctx regs: lane holds ctx[q=lr][hd = lg*4 + r (+16)]
        short* cp = ctx + ((size_t)(b * Ssz + q0 + lr)) * Dsz + h * HDd + lg * 4;
#pragma unroll
        for (int r = 0; r < 4; r++) {
            cp[r]      = f2bf(acc0[r] * inv);
            cp[16 + r] = f2bf(acc1[r] * inv);
        }
    } else {
        const size_t row = ((size_t)blockIdx.z * (Bsz * Hh) + bh) * Ssz + (q0 + lr);
        short* pa = pacc + row * HDd;
        u2 a = {cvtpk(acc0[0], acc0[1]), cvtpk(acc0[2], acc0[3])};
        u2 c = {cvtpk(acc1[0], acc1[1]), cvtpk(acc1[2], acc1[3])};
        *(u2*)(pa + lg * 4)      = a;
        *(u2*)(pa + 16 + lg * 4) = c;
        if (lg == 0) {
            pms[row * 2]     = mx;
            pms[row * 2 + 1] = sum;
        }
    }
}

// ---------------- split-KV combine: LSE merge of the two halves ----------------
__global__ __launch_bounds__(256) void combine(
    const short* __restrict__ pacc, const float* __restrict__ pms,
    short* __restrict__ ctx)
{
    const int t = blockIdx.x * 256 + threadIdx.x;     // (bh*2048+q)*4 + quarter
    const int row = t >> 2, qt = t & 3;
    const int bh = row >> 11, q = row & 2047;
    const int b = bh >> 3, h = bh & 7;
    const size_t R = (size_t)(Bsz * Hh) * Ssz;
    float m0 = pms[(size_t)row * 2],     s0 = pms[(size_t)row * 2 + 1];
    float m1 = pms[(R + row) * 2],       s1 = pms[(R + row) * 2 + 1];
    float m = fmaxf(m0, m1);
    float w0 = fexp2(m0 - m), w1 = fexp2(m1 - m);
    float inv = 1.f / (s0 * w0 + s1 * w1);
    w0 *= inv; w1 *= inv;
    bh8 v0 = *(const bh8*)(pacc + (size_t)row * HDd + qt * 8);
    bh8 v1 = *(const bh8*)(pacc + (R + row) * HDd + qt * 8);
    bh8 o;
#pragma unroll
    for (int j = 0; j < 8; j++)
        o[j] = f2bf(bf2f(v0[j]) * w0 + bf2f(v1[j]) * w1);
    *(bh8*)(ctx + ((size_t)(b * Ssz + q)) * Dsz + h * HDd + qt * 8) = o;
}

// ---------------- output projection (1-wave blocks for CU balance) ----------------
__global__ __launch_bounds__(64) void out_gemm(
    const short* __restrict__ ctx, const short* __restrict__ WtO,
    const float* __restrict__ bo, float* __restrict__ out)
{
    const int lane = threadIdx.x;
    const int lg = lane >> 4, lr = lane & 15;
    const int m0 = blockIdx.x * 16;
    f4 acc[16];
#pragma unroll
    for (int t = 0; t < 16; t++) acc[t] = (f4){0.f, 0.f, 0.f, 0.f};
    const short* ap = ctx + (size_t)(m0 + lr) * 256 + lg * 8;
#pragma unroll
    for (int k0 = 0; k0 < 256; k0 += 32) {
        bh8 af = *(const bh8*)(ap + k0);
#pragma unroll
        for (int nt = 0; nt < 16; nt++) {
            bh8 bf = *(const bh8*)(WtO + (nt * 16 + lr) * 256 + k0 + lg * 8);
            acc[nt] = __builtin_amdgcn_mfma_f32_16x16x32_bf16(af, bf, acc[nt], 0, 0, 0);
        }
    }
#pragma unroll
    for (int nt = 0; nt < 16; nt++) {
        const int n = nt * 16 + lr;
        const float bias = bo[n];
#pragma unroll
        for (int r = 0; r < 4; r++) {
            out[(size_t)(m0 + lg * 4 + r) * 256 + n] = acc[nt][r] + bias;
        }
    }
}

extern "C" void kernel_launch(void* const* d_in, const int* in_sizes, int n_in,
                              void* d_out, int out_size, void* d_ws, size_t ws_size,
                              hipStream_t stream)
{
    const float* hid  = (const float*)d_in[0];
    const float* pos  = (const float*)d_in[1];
    const float* mask = (const float*)d_in[2];
    const float* Wq   = (const float*)d_in[3];
    const float* bq   = (const float*)d_in[4];
    const float* Wk   = (const float*)d_in[5];
    const float* bk   = (const float*)d_in[6];
    const float* Wv   = (const float*)d_in[7];
    const float* bv   = (const float*)d_in[8];
    const float* Wo   = (const float*)d_in[9];
    const float* bo   = (const float*)d_in[10];
    float* out = (float*)d_out;

    char* ws = (char*)d_ws;
    short* Wt   = (short*)(ws);                    // 512 KB: Wq^T,Wk^T,Wv^T,Wo^T bf16
    float* bqs  = (float*)(ws + (512 << 10));      // 1 KB
    int*   flag = (int*)  (ws + (516 << 10));      // 4 B
    short* Qb   = (short*)(ws + (1  << 20));       // 4 MB  [B,H,S,32] bf16
    short* Kb   = (short*)(ws + (5  << 20));       // 4 MB  [B,H,S,32] bf16
    short* Vtb  = (short*)(ws + (9  << 20));       // 4 MB  [B,H,32,S] bf16 (k-slot permuted)
    short* ctxb = (short*)(ws + (13 << 20));       // 4 MB  [B,S,256] bf16
    short* pacc = (short*)(ws + (17 << 20));       // 8.4 MB [2,B*H,S,32] bf16 partials
    float* pms  = (float*)(ws + (26 << 20));       // 1.05 MB [2,B*H,S,2] (mx, sum)

    prep_w<<<256, 256, 0, stream>>>(Wq, Wk, Wv, Wo, bq, Wt, bqs, flag);
    scan_mask<<<2048, 256, 0, stream>>>(mask, flag);
    qkv_gemm<<<dim3(512, 3), 64, 0, stream>>>(hid, pos, Wt, bqs, bk, bv, Qb, Kb, Vtb);

    const bool split = ws_size >= ((size_t)28 << 20);
    if (split) {
        attn<2><<<dim3(32, 32, 2), 256, 0, stream>>>(Qb, Kb, Vtb, mask, flag, ctxb, pacc, pms);
        combine<<<1024, 256, 0, stream>>>(pacc, pms, ctxb);
    } else {
        attn<1><<<dim3(32, 32, 1), 256, 0, stream>>>(Qb, Kb, Vtb, mask, flag, ctxb, pacc, pms);
    }
    out_gemm<<<512, 64, 0, stream>>>(ctxb, Wt + 196608, bo, out);
}

// Round 4
// 114.393 us; speedup vs baseline: 2.1344x; 1.6000x over previous
//
#include <hip/hip_runtime.h>
#include <hip/hip_bf16.h>

#define Bsz 4
#define Ssz 2048
#define Dsz 256
#define Hh 8
#define HDd 32

typedef __attribute__((ext_vector_type(8))) short bh8;
typedef __attribute__((ext_vector_type(4))) float f4;
typedef __attribute__((ext_vector_type(2))) unsigned u2;

#define SCAL 0.17677669529663687f   /* 32^-0.5 */
#define LOG2E 1.4426950408889634f
#define QSCALE (SCAL * LOG2E)

__device__ __forceinline__ short f2bf(float f) {
    union { float f; unsigned u; } x; x.f = f;
    unsigned r = x.u + 0x7fffu + ((x.u >> 16) & 1u);
    return (short)(r >> 16);
}

__device__ __forceinline__ float bf2f(short s) {
    union { unsigned u; float f; } x;
    x.u = ((unsigned)(unsigned short)s) << 16;
    return x.f;
}

__device__ __forceinline__ float fexp2(float x) {
#if __has_builtin(__builtin_amdgcn_exp2f)
    return __builtin_amdgcn_exp2f(x);
#else
    float r; asm("v_exp_f32 %0, %1" : "=v"(r) : "v"(x)); return r;
#endif
}

__device__ __forceinline__ unsigned cvtpk(float lo, float hi) {
    unsigned r; asm("v_cvt_pk_bf16_f32 %0, %1, %2" : "=v"(r) : "v"(lo), "v"(hi));
    return r;
}

__device__ __forceinline__ void gload16(const void* g, void* l) {
    __builtin_amdgcn_global_load_lds(
        (const __attribute__((address_space(1))) unsigned int*)g,
        (__attribute__((address_space(3))) unsigned int*)l, 16, 0, 0);
}

// ---------------- weight prep: transpose to [n][d] bf16, fold q scaling ----------------
__global__ __launch_bounds__(256) void prep_w(
    const float* __restrict__ Wq, const float* __restrict__ Wk,
    const float* __restrict__ Wv, const float* __restrict__ Wo,
    const float* __restrict__ bq, short* __restrict__ Wt,
    float* __restrict__ bqs, int* __restrict__ flag)
{
    int t = blockIdx.x * 256 + threadIdx.x;   // t = d*256 + n
    int d = t >> 8, n = t & 255;
    int o = n * 256 + d;
    Wt[o]          = f2bf(Wq[t] * QSCALE);
    Wt[65536 + o]  = f2bf(Wk[t]);
    Wt[131072 + o] = f2bf(Wv[t]);
    Wt[196608 + o] = f2bf(Wo[t]);
    if (t == 0) *flag = 0;
    if (t < 256) bqs[t] = bq[t] * QSCALE;
}

// ---------------- hp = bf16(hid+pos), hv = bf16(hid) ----------------
__global__ __launch_bounds__(256) void prep_hp(
    const float* __restrict__ hid, const float* __restrict__ pos,
    short* __restrict__ hp, short* __restrict__ hv)
{
    const size_t i = ((size_t)blockIdx.x * 256 + threadIdx.x) * 8;
    f4 h1 = *(const f4*)(hid + i), h2 = *(const f4*)(hid + i + 4);
    f4 p1 = *(const f4*)(pos + i), p2 = *(const f4*)(pos + i + 4);
    union { unsigned u[4]; bh8 v; } a, b;
    a.u[0] = cvtpk(h1[0] + p1[0], h1[1] + p1[1]);
    a.u[1] = cvtpk(h1[2] + p1[2], h1[3] + p1[3]);
    a.u[2] = cvtpk(h2[0] + p2[0], h2[1] + p2[1]);
    a.u[3] = cvtpk(h2[2] + p2[2], h2[3] + p2[3]);
    b.u[0] = cvtpk(h1[0], h1[1]); b.u[1] = cvtpk(h1[2], h1[3]);
    b.u[2] = cvtpk(h2[0], h2[1]); b.u[3] = cvtpk(h2[2], h2[3]);
    *(bh8*)(hp + i) = a.v;
    *(bh8*)(hv + i) = b.v;
}

// ---------------- mask scan: set flag if any nonzero ----------------
__global__ __launch_bounds__(256) void scan_mask(const float* __restrict__ mask,
                                                 int* __restrict__ flag)
{
    const size_t N4 = (size_t)Bsz * Ssz * Ssz / 4;
    const f4* m4 = (const f4*)mask;
    bool nz = false;
    for (size_t i = blockIdx.x * 256 + threadIdx.x; i < N4; i += (size_t)gridDim.x * 256) {
        f4 v = m4[i];
        nz |= (v[0] != 0.f) || (v[1] != 0.f) || (v[2] != 0.f) || (v[3] != 0.f);
    }
    if (nz) atomicOr(flag, 1);
}

// ---------------- fused QKV projection ----------------
// grid (512, 3), 256 thr: block = 16-row tile; wave w = 64-col quarter.
// y=0 -> Q (scaled), y=1 -> K, y=2 -> V^T (k-slot permuted per 32 keys)
__global__ __launch_bounds__(256) void qkv_gemm(
    const short* __restrict__ hp, const short* __restrict__ hv,
    const short* __restrict__ Wt, const float* __restrict__ bqs,
    const float* __restrict__ bk, const float* __restrict__ bv,
    short* __restrict__ Q, short* __restrict__ K, short* __restrict__ Vt)
{
    const int ky = blockIdx.y;
    const int w = threadIdx.x >> 6, lane = threadIdx.x & 63;
    const int lg = lane >> 4, lr = lane & 15;
    const int m0 = blockIdx.x * 16;
    const short* A = (ky < 2) ? hp : hv;
    const short* W = Wt + ky * 65536;
    f4 acc[4];
#pragma unroll
    for (int t = 0; t < 4; t++) acc[t] = (f4){0.f, 0.f, 0.f, 0.f};

    const short* ap = A + (size_t)(m0 + lr) * 256 + lg * 8;
#pragma unroll
    for (int k0 = 0; k0 < 256; k0 += 32) {
        bh8 af = *(const bh8*)(ap + k0);
#pragma unroll
        for (int nt = 0; nt < 4; nt++) {
            bh8 bf = *(const bh8*)(W + (size_t)(w * 64 + nt * 16 + lr) * 256 + k0 + lg * 8);
            acc[nt] = __builtin_amdgcn_mfma_f32_16x16x32_bf16(af, bf, acc[nt], 0, 0, 0);
        }
    }
    const int b = m0 >> 11;
    const int s0 = m0 & 2047;
#pragma unroll
    for (int nt = 0; nt < 4; nt++) {
        const int n = w * 64 + nt * 16 + lr;
        const int h = n >> 5, hd = n & 31;
#pragma unroll
        for (int r = 0; r < 4; r++) {
            const int s = s0 + lg * 4 + r;
            float v = acc[nt][r];
            if (ky == 0) {
                v += bqs[n];
                Q[(((size_t)(b * Hh + h)) * Ssz + s) * HDd + hd] = f2bf(v);
            } else if (ky == 1) {
                v += bk[n];
                K[(((size_t)(b * Hh + h)) * Ssz + s) * HDd + hd] = f2bf(v);
            } else {
                v += bv[n];
                // permute key within its 32-block into MFMA k-slot order
                int s32 = s & 31;
                int ps = ((s32 & 15) >> 2) * 8 + (s32 >> 4) * 4 + (s32 & 3);
                Vt[(((size_t)(b * Hh + h)) * HDd + hd) * Ssz + (s & ~31) + ps] = f2bf(v);
            }
        }
    }
}

// ---------------- flash attention, LDS-staged double-buffered KV ----------------
// grid (S/64, B*H, NS), 4 waves/block, each wave owns 16 q rows, KV tile = 64.
// LDS per buffer: K 4KB (64 keys x 64B, XOR-swz) + V 4KB (32 hd x 128B, XOR-swz).
template<int NS>
__global__ __launch_bounds__(256) void attn(
    const short* __restrict__ Q, const short* __restrict__ Kb,
    const short* __restrict__ Vt, const float* __restrict__ mask,
    const int* __restrict__ flag, short* __restrict__ ctx,
    short* __restrict__ pacc, float* __restrict__ pms)
{
    __shared__ __align__(16) char lds[16384];
    const int tid = threadIdx.x;
    const int bh = blockIdx.y, b = bh >> 3, h = bh & 7;
    const int w = tid >> 6, lane = tid & 63;
    const int lg = lane >> 4, lr = lane & 15;
    const int q0 = blockIdx.x * 64 + w * 16;
    const int kz0 = blockIdx.z * (Ssz / NS);
    constexpr int NT = Ssz / NS / 64;

    const char* Kg = (const char*)(Kb + (size_t)bh * Ssz * HDd);
    const char* Vg = (const char*)(Vt + (size_t)bh * HDd * Ssz);
    const float* mrow = mask + ((size_t)b * Ssz + q0 + lr) * Ssz;
    const bool um = (*flag) != 0;

    // staging: thread tid stages 16B of K and 16B of V; source pre-swizzled (rule 21)
    const int kx = (tid * 16) ^ (((tid >> 3) & 3) << 4);
    const int vrow = tid >> 3;
    const int vcol = ((tid & 7) * 16) ^ ((vrow & 7) << 4);
    const char* kgp = Kg + (size_t)kz0 * 64 + kx;
    const char* vgp = Vg + (size_t)vrow * (Ssz * 2) + (size_t)kz0 * 2 + vcol;
    char* ldsK = lds + w * 1024;          // wave-uniform dests
    char* ldsV = lds + 4096 + w * 1024;

    // swizzled read offsets
    const int koff  = (lr * 64 + lg * 16) ^ (((lr >> 1) & 3) << 4);
    const int voff0 = 4096 + ((lr * 128 + lg * 16) ^ ((lr & 7) << 4));
    const int voff1 = voff0 ^ 64;

    bh8 qf = *(const bh8*)(Q + ((size_t)bh * Ssz + q0 + lr) * HDd + lg * 8);
    f4 acc0 = {0.f, 0.f, 0.f, 0.f}, acc1 = {0.f, 0.f, 0.f, 0.f};
    float mx = -1e30f, sumP = 0.f;
    const f4 z = {0.f, 0.f, 0.f, 0.f};

    // stage tile 0 -> buf0
    gload16(kgp, ldsK);
    gload16(vgp, ldsV);

    auto compute = [&](int t, int bs) {
        const char* kp = lds + bs + koff;
        bh8 k0 = *(const bh8*)(kp);
        bh8 k1 = *(const bh8*)(kp + 1024);
        bh8 k2 = *(const bh8*)(kp + 2048);
        bh8 k3 = *(const bh8*)(kp + 3072);
        const char* vp = lds + bs;
        bh8 v00 = *(const bh8*)(vp + voff0);
        bh8 v01 = *(const bh8*)(vp + voff1);
        bh8 v10 = *(const bh8*)(vp + voff0 + 2048);
        bh8 v11 = *(const bh8*)(vp + voff1 + 2048);

        f4 s0 = __builtin_amdgcn_mfma_f32_16x16x32_bf16(k0, qf, z, 0, 0, 0);
        f4 s1 = __builtin_amdgcn_mfma_f32_16x16x32_bf16(k1, qf, z, 0, 0, 0);
        f4 s2 = __builtin_amdgcn_mfma_f32_16x16x32_bf16(k2, qf, z, 0, 0, 0);
        f4 s3 = __builtin_amdgcn_mfma_f32_16x16x32_bf16(k3, qf, z, 0, 0, 0);
        if (um) {
            const int kb = kz0 + t * 64;
            f4 m0v = *(const f4*)(mrow + kb + lg * 4);
            f4 m1v = *(const f4*)(mrow + kb + 16 + lg * 4);
            f4 m2v = *(const f4*)(mrow + kb + 32 + lg * 4);
            f4 m3v = *(const f4*)(mrow + kb + 48 + lg * 4);
            s0 += m0v * LOG2E; s1 += m1v * LOG2E; s2 += m2v * LOG2E; s3 += m3v * LOG2E;
        }

        float ta = fmaxf(fmaxf(s0[0], s0[1]), fmaxf(s0[2], s0[3]));
        float tb = fmaxf(fmaxf(s1[0], s1[1]), fmaxf(s1[2], s1[3]));
        float tc = fmaxf(fmaxf(s2[0], s2[1]), fmaxf(s2[2], s2[3]));
        float td = fmaxf(fmaxf(s3[0], s3[1]), fmaxf(s3[2], s3[3]));
        float tm = fmaxf(fmaxf(ta, tb), fmaxf(tc, td));
        if (!__all(tm <= mx + 8.f)) {
            tm = fmaxf(tm, __shfl_xor(tm, 16));
            tm = fmaxf(tm, __shfl_xor(tm, 32));
            float nm = fmaxf(mx, tm);
            float alpha = fexp2(mx - nm);
            mx = nm;
#pragma unroll
            for (int r = 0; r < 4; r++) { acc0[r] *= alpha; acc1[r] *= alpha; }
            sumP *= alpha;
        }

        float p[16];
#pragma unroll
        for (int j = 0; j < 4; j++) {
            p[j]      = fexp2(s0[j] - mx);
            p[4 + j]  = fexp2(s1[j] - mx);
            p[8 + j]  = fexp2(s2[j] - mx);
            p[12 + j] = fexp2(s3[j] - mx);
        }
        sumP += ((p[0] + p[1]) + (p[2] + p[3])) + ((p[4] + p[5]) + (p[6] + p[7]))
              + ((p[8] + p[9]) + (p[10] + p[11])) + ((p[12] + p[13]) + (p[14] + p[15]));

        union { unsigned u[4]; bh8 v; } pf0, pf1;
        pf0.u[0] = cvtpk(p[0], p[1]);   pf0.u[1] = cvtpk(p[2], p[3]);
        pf0.u[2] = cvtpk(p[4], p[5]);   pf0.u[3] = cvtpk(p[6], p[7]);
        pf1.u[0] = cvtpk(p[8], p[9]);   pf1.u[1] = cvtpk(p[10], p[11]);
        pf1.u[2] = cvtpk(p[12], p[13]); pf1.u[3] = cvtpk(p[14], p[15]);

        acc0 = __builtin_amdgcn_mfma_f32_16x16x32_bf16(v00, pf0.v, acc0, 0, 0, 0);
        acc0 = __builtin_amdgcn_mfma_f32_16x16x32_bf16(v01, pf1.v, acc0, 0, 0, 0);
        acc1 = __builtin_amdgcn_mfma_f32_16x16x32_bf16(v10, pf0.v, acc1, 0, 0, 0);
        acc1 = __builtin_amdgcn_mfma_f32_16x16x32_bf16(v11, pf1.v, acc1, 0, 0, 0);
    };

    for (int t = 0; t < NT - 1; ++t) {
        // stage t+1 into the other buffer (prev iter's trailing barrier made it safe)
        const int bn = ((t + 1) & 1) << 13;
        gload16(kgp + (size_t)(t + 1) * 4096, ldsK + bn);
        gload16(vgp + (size_t)(t + 1) * 128,  ldsV + bn);
        asm volatile("s_waitcnt vmcnt(2)" ::: "memory");  // current buf landed (mine)
        __builtin_amdgcn_s_barrier();                      // everyone's landed
        compute(t, (t & 1) << 13);
        __builtin_amdgcn_s_barrier();                      // all reads of this buf done
    }
    asm volatile("s_waitcnt vmcnt(0)" ::: "memory");
    __builtin_amdgcn_s_barrier();
    compute(NT - 1, ((NT - 1) & 1) << 13);

    // deferred cross-lane sum reduction (alpha was row-uniform throughout)
    float sum = sumP;
    sum += __shfl_xor(sum, 16);
    sum += __shfl_xor(sum, 32);

    if constexpr (NS == 1) {
        float inv = 1.f / sum;
        short* cp = ctx + ((size_t)(b * Ssz + q0 + lr)) * Dsz + h * HDd + lg * 4;
#pragma unroll
        for (int r = 0; r < 4; r++) {
            cp[r]      = f2bf(acc0[r] * inv);
            cp[16 + r] = f2bf(acc1[r] * inv);
        }
    } else {
        const size_t row = ((size_t)blockIdx.z * (Bsz * Hh) + bh) * Ssz + (q0 + lr);
        short* pa = pacc + row * HDd;
        u2 a = {cvtpk(acc0[0], acc0[1]), cvtpk(acc0[2], acc0[3])};
        u2 c = {cvtpk(acc1[0], acc1[1]), cvtpk(acc1[2], acc1[3])};
        *(u2*)(pa + lg * 4)      = a;
        *(u2*)(pa + 16 + lg * 4) = c;
        if (lg == 0) {
            pms[row * 2]     = mx;
            pms[row * 2 + 1] = sum;
        }
    }
}

// ---------------- split-KV combine: LSE merge of the two halves ----------------
__global__ __launch_bounds__(256) void combine(
    const short* __restrict__ pacc, const float* __restrict__ pms,
    short* __restrict__ ctx)
{
    const int t = blockIdx.x * 256 + threadIdx.x;     // (bh*2048+q)*4 + quarter
    const int row = t >> 2, qt = t & 3;
    const int bh = row >> 11, q = row & 2047;
    const int b = bh >> 3, h = bh & 7;
    const size_t R = (size_t)(Bsz * Hh) * Ssz;
    float m0 = pms[(size_t)row * 2],     s0 = pms[(size_t)row * 2 + 1];
    float m1 = pms[(R + row) * 2],       s1 = pms[(R + row) * 2 + 1];
    float m = fmaxf(m0, m1);
    float w0 = fexp2(m0 - m), w1 = fexp2(m1 - m);
    float inv = 1.f / (s0 * w0 + s1 * w1);
    w0 *= inv; w1 *= inv;
    bh8 v0 = *(const bh8*)(pacc + (size_t)row * HDd + qt * 8);
    bh8 v1 = *(const bh8*)(pacc + (R + row) * HDd + qt * 8);
    bh8 o;
#pragma unroll
    for (int j = 0; j < 8; j++)
        o[j] = f2bf(bf2f(v0[j]) * w0 + bf2f(v1[j]) * w1);
    *(bh8*)(ctx + ((size_t)(b * Ssz + q)) * Dsz + h * HDd + qt * 8) = o;
}

// ---------------- output projection: block = 16-row tile, wave = 64-col quarter ----------------
__global__ __launch_bounds__(256) void out_gemm(
    const short* __restrict__ ctx, const short* __restrict__ WtO,
    const float* __restrict__ bo, float* __restrict__ out)
{
    const int w = threadIdx.x >> 6, lane = threadIdx.x & 63;
    const int lg = lane >> 4, lr = lane & 15;
    const int m0 = blockIdx.x * 16;
    f4 acc[4];
#pragma unroll
    for (int t = 0; t < 4; t++) acc[t] = (f4){0.f, 0.f, 0.f, 0.f};
    const short* ap = ctx + (size_t)(m0 + lr) * 256 + lg * 8;
#pragma unroll
    for (int k0 = 0; k0 < 256; k0 += 32) {
        bh8 af = *(const bh8*)(ap + k0);
#pragma unroll
        for (int nt = 0; nt < 4; nt++) {
            bh8 bf = *(const bh8*)(WtO + (size_t)(w * 64 + nt * 16 + lr) * 256 + k0 + lg * 8);
            acc[nt] = __builtin_amdgcn_mfma_f32_16x16x32_bf16(af, bf, acc[nt], 0, 0, 0);
        }
    }
#pragma unroll
    for (int nt = 0; nt < 4; nt++) {
        const int n = w * 64 + nt * 16 + lr;
        const float bias = bo[n];
#pragma unroll
        for (int r = 0; r < 4; r++) {
            out[(size_t)(m0 + lg * 4 + r) * 256 + n] = acc[nt][r] + bias;
        }
    }
}

extern "C" void kernel_launch(void* const* d_in, const int* in_sizes, int n_in,
                              void* d_out, int out_size, void* d_ws, size_t ws_size,
                              hipStream_t stream)
{
    const float* hid  = (const float*)d_in[0];
    const float* pos  = (const float*)d_in[1];
    const float* mask = (const float*)d_in[2];
    const float* Wq   = (const float*)d_in[3];
    const float* bq   = (const float*)d_in[4];
    const float* Wk   = (const float*)d_in[5];
    const float* bk   = (const float*)d_in[6];
    const float* Wv   = (const float*)d_in[7];
    const float* bv   = (const float*)d_in[8];
    const float* Wo   = (const float*)d_in[9];
    const float* bo   = (const float*)d_in[10];
    float* out = (float*)d_out;

    char* ws = (char*)d_ws;
    short* Wt   = (short*)(ws);                    // 512 KB: Wq^T,Wk^T,Wv^T,Wo^T bf16
    float* bqs  = (float*)(ws + (512 << 10));      // 1 KB
    int*   flag = (int*)  (ws + (516 << 10));      // 4 B
    short* hp   = (short*)(ws + (1  << 20));       // 4 MB  bf16(hid+pos)
    short* hv   = (short*)(ws + (5  << 20));       // 4 MB  bf16(hid)
    short* Qb   = (short*)(ws + (9  << 20));       // 4 MB  [B,H,S,32]
    short* Kb   = (short*)(ws + (13 << 20));       // 4 MB  [B,H,S,32]
    short* Vtb  = (short*)(ws + (17 << 20));       // 4 MB  [B,H,32,S] (k-slot permuted)
    short* ctxb = (short*)(ws + (21 << 20));       // 4 MB  [B,S,256]
    short* pacc = (short*)(ws + (25 << 20));       // 8.4 MB [2,B*H,S,32] partials
    float* pms  = (float*)(ws + (34 << 20));       // 1.05 MB [2,B*H,S,2] (mx,sum)

    prep_w<<<256, 256, 0, stream>>>(Wq, Wk, Wv, Wo, bq, Wt, bqs, flag);
    prep_hp<<<1024, 256, 0, stream>>>(hid, pos, hp, hv);
    scan_mask<<<2048, 256, 0, stream>>>(mask, flag);
    qkv_gemm<<<dim3(512, 3), 256, 0, stream>>>(hp, hv, Wt, bqs, bk, bv, Qb, Kb, Vtb);

    const bool split = ws_size >= ((size_t)36 << 20);
    if (split) {
        attn<2><<<dim3(32, 32, 2), 256, 0, stream>>>(Qb, Kb, Vtb, mask, flag, ctxb, pacc, pms);
        combine<<<1024, 256, 0, stream>>>(pacc, pms, ctxb);
    } else {
        attn<1><<<dim3(32, 32, 1), 256, 0, stream>>>(Qb, Kb, Vtb, mask, flag, ctxb, pacc, pms);
    }
    out_gemm<<<512, 256, 0, stream>>>(ctxb, Wt + 196608, bo, out);
}